// Round 15
// baseline (176.403 us; speedup 1.0000x reference)
//
#include <hip/hip_runtime.h>
#include <hip/hip_bf16.h>

#define SEQ   512
#define BATCH 1024
#define HD    64
#define NS    4      // samples per block -> 256 blocks (1 block/CU)
#define TB    16     // time-batch: steps per x-projection pass

typedef __attribute__((ext_vector_type(8))) short bf16x8;   // 8 bf16 = 4 VGPR
typedef __attribute__((ext_vector_type(4))) float f32x4;    // MFMA acc

// float -> bf16 raw bits, round-to-nearest-even
__device__ __forceinline__ unsigned short f2bf(float f) {
    unsigned u = __float_as_uint(f);
    return (unsigned short)((u + 0x7FFFu + ((u >> 16) & 1u)) >> 16);
}
__device__ __forceinline__ float frcp(float x) { return __builtin_amdgcn_rcpf(x); }
// raw v_exp_f32 (exp2), 1 instruction on the chain
__device__ __forceinline__ float fexp2(float x) {
    float r; asm("v_exp_f32 %0, %1" : "=v"(r) : "v"(x)); return r;
}
// Raw workgroup barrier: orders LDS (lgkmcnt) but does NOT drain vmcnt --
// in-flight global out-stores (never read back) stay in flight across steps.
// __syncthreads() would emit s_waitcnt vmcnt(0) putting the store ack
// (~150-250 cyc) on the per-step serial chain. sched_barrier(0) pins the
// surrounding memory ops (guide rule #18).
__device__ __forceinline__ void wg_barrier() {
    __builtin_amdgcn_sched_barrier(0);
    asm volatile("s_waitcnt lgkmcnt(0)" ::: "memory");
    __builtin_amdgcn_s_barrier();
    __builtin_amdgcn_sched_barrier(0);
}

// v12: latency-bound recurrence; chain = barrier -> ds_read h -> 8 indep
// MFMA -> cell -> writes -> barrier. This round: (1) xg layout
// [NS][16][17][19] + scalar writes => xg reads hit all 32 banks 2-way
// (free) vs v11's 8-way (13.6M conflict cycles); (2) hb pad 80 (v6's
// zero-conflict layout); (3) raw lgkmcnt-only barrier (no vmcnt drain);
// (4) c carried pre-scaled by -2log2e (one fewer chain op).
__global__ __launch_bounds__(256, 1)
void lstm_v12(const float* __restrict__ x,
              const float* __restrict__ W_ih,
              const float* __restrict__ W_hh,
              const float* __restrict__ b_ih,
              const float* __restrict__ b_hh,
              float* __restrict__ out)
{
    __shared__ float xgf[NS * 16 * 17 * 19];                  // 80.75 KB [m][tile][col+pad][step+pad]
    __shared__ __align__(16) unsigned short xch[NS][TB][72];  // 9 KB  [m][step][k+pad]
    __shared__ __align__(16) unsigned short hb[2][NS][80];    // 1.25 KB ping-pong h

    const int tid  = threadIdx.x;
    const int w    = tid >> 6;        // wave 0..3
    const int ln   = tid & 63;
    const int col  = ln & 15;         // MFMA col / unit within wave
    const int kg   = ln >> 4;         // k-group of fragments
    const int slot = (ln >> 2) & 3;   // A-row -> sample (v6-verified map)
    const int q    = ln >> 4;         // cell sample (D row 4q reg0)
    const int unit = w * 16 + col;
    const int sBase = blockIdx.x * NS;

    const float L2E = 1.4426950408889634f;
    const float sc[4] = { -L2E, -L2E, -2.f * L2E, -L2E };  // i,f,g,o pre-scales

    // ---- one-time: pre-scaled W_ih / W_hh B-fragments -> registers ----
    bf16x8 Bx[4][2], Bh[4][2];        // [gate][k-tile]
    #pragma unroll
    for (int g = 0; g < 4; ++g) {
        const float s = sc[g];
        #pragma unroll
        for (int kt = 0; kt < 2; ++kt) {
            const int n = (g * 4 + w) * 16 + col;
            const int k = kt * 32 + kg * 8;
            const float4 xa = *(const float4*)(W_ih + n * 64 + k);
            const float4 xb = *(const float4*)(W_ih + n * 64 + k + 4);
            const float4 ha = *(const float4*)(W_hh + n * 64 + k);
            const float4 hc = *(const float4*)(W_hh + n * 64 + k + 4);
            bf16x8 vx, vh;
            vx[0]=(short)f2bf(xa.x*s); vx[1]=(short)f2bf(xa.y*s); vx[2]=(short)f2bf(xa.z*s); vx[3]=(short)f2bf(xa.w*s);
            vx[4]=(short)f2bf(xb.x*s); vx[5]=(short)f2bf(xb.y*s); vx[6]=(short)f2bf(xb.z*s); vx[7]=(short)f2bf(xb.w*s);
            vh[0]=(short)f2bf(ha.x*s); vh[1]=(short)f2bf(ha.y*s); vh[2]=(short)f2bf(ha.z*s); vh[3]=(short)f2bf(ha.w*s);
            vh[4]=(short)f2bf(hc.x*s); vh[5]=(short)f2bf(hc.y*s); vh[6]=(short)f2bf(hc.z*s); vh[7]=(short)f2bf(hc.w*s);
            Bx[g][kt] = vx; Bh[g][kt] = vh;
        }
    }
    // pre-scaled bias -> x-pass C operand
    f32x4 bias4[4];
    #pragma unroll
    for (int g = 0; g < 4; ++g) {
        const int gg = g * 64 + unit;
        const float b = (b_ih[gg] + b_hh[gg]) * sc[g];
        bias4[g][0] = b; bias4[g][1] = b; bias4[g][2] = b; bias4[g][3] = b;
    }
    // per-lane xg read bases (loop-invariant): bank = q*16 + col*19 + tc
    // -> 32 banks x 2 lanes = conflict-free
    int xbase[4];
    #pragma unroll
    for (int g = 0; g < 4; ++g)
        xbase[g] = ((q * 16 + g * 4 + w) * 17 + col) * 19;

    for (int i = tid; i < (2 * NS * 80) / 2; i += 256) ((unsigned*)hb)[i] = 0;

    float Cs = 0.f;                   // c pre-scaled by -2log2e
    const f32x4 z4 = {0.f, 0.f, 0.f, 0.f};
    float* outp = out + (size_t)(sBase + q) * HD + unit;

    for (int T = 0; T < SEQ; T += TB) {
        // ---- refill x chunk: 1024 float4 / 256 thr = 4 each ----
        #pragma unroll
        for (int j = 0; j < 4; ++j) {
            const int idx = tid + j * 256;
            const int k4 = idx & 15, tt = (idx >> 4) & 15, m = idx >> 8;
            const float4 v = *(const float4*)&x[(((size_t)(T + tt) * BATCH) + sBase + m) * HD + k4 * 4];
            uint2 pk;
            pk.x = (unsigned)f2bf(v.x) | ((unsigned)f2bf(v.y) << 16);
            pk.y = (unsigned)f2bf(v.z) | ((unsigned)f2bf(v.w) << 16);
            *(uint2*)&xch[m][tt][k4 * 4] = pk;
        }
        wg_barrier();

        // ---- x-pass: per sample, A-rows = 16 timesteps; bias in C ----
        #pragma unroll
        for (int m = 0; m < NS; ++m) {
            const bf16x8 a0 = *(const bf16x8*)&xch[m][ln & 15][kg * 8];
            const bf16x8 a1 = *(const bf16x8*)&xch[m][ln & 15][32 + kg * 8];
            #pragma unroll
            for (int g = 0; g < 4; ++g) {
                f32x4 a = __builtin_amdgcn_mfma_f32_16x16x32_bf16(a0, Bx[g][0], bias4[g], 0, 0, 0);
                a = __builtin_amdgcn_mfma_f32_16x16x32_bf16(a1, Bx[g][1], a, 0, 0, 0);
                // D rows = steps 4kg..4kg+3; scalar writes (layout has odd strides)
                const int base = ((m * 16 + g * 4 + w) * 17 + col) * 19 + 4 * kg;
                xgf[base + 0] = a[0]; xgf[base + 1] = a[1];
                xgf[base + 2] = a[2]; xgf[base + 3] = a[3];
            }
        }
        // no barrier: wave w reads only tiles {4g+w} -- its own writes

        // xg prefetch for step 0 (register-carried across barriers)
        float xgi = xgf[xbase[0]];
        float xgf_ = xgf[xbase[1]];
        float xgg = xgf[xbase[2]];
        float xgo = xgf[xbase[3]];

        #pragma unroll
        for (int tc = 0; tc < TB; ++tc) {
            const int pr = tc & 1;                 // static ping-pong index
            const bf16x8 ah0 = *(const bf16x8*)&hb[pr][slot][kg * 8];
            const bf16x8 ah1 = *(const bf16x8*)&hb[pr][slot][32 + kg * 8];

            // 8 INDEPENDENT MFMAs (K-halves merged by scalar adds)
            const f32x4 il = __builtin_amdgcn_mfma_f32_16x16x32_bf16(ah0, Bh[0][0], z4, 0, 0, 0);
            const f32x4 ih = __builtin_amdgcn_mfma_f32_16x16x32_bf16(ah1, Bh[0][1], z4, 0, 0, 0);
            const f32x4 fl = __builtin_amdgcn_mfma_f32_16x16x32_bf16(ah0, Bh[1][0], z4, 0, 0, 0);
            const f32x4 fh = __builtin_amdgcn_mfma_f32_16x16x32_bf16(ah1, Bh[1][1], z4, 0, 0, 0);
            const f32x4 gl = __builtin_amdgcn_mfma_f32_16x16x32_bf16(ah0, Bh[2][0], z4, 0, 0, 0);
            const f32x4 gh = __builtin_amdgcn_mfma_f32_16x16x32_bf16(ah1, Bh[2][1], z4, 0, 0, 0);
            const f32x4 ol = __builtin_amdgcn_mfma_f32_16x16x32_bf16(ah0, Bh[3][0], z4, 0, 0, 0);
            const f32x4 oh = __builtin_amdgcn_mfma_f32_16x16x32_bf16(ah1, Bh[3][1], z4, 0, 0, 0);

            // pre-activations (already scaled by -l2e / -2l2e, bias included)
            const float Pi = xgi  + il[0] + ih[0];
            const float Pf = xgf_ + fl[0] + fh[0];
            const float Pg = xgg  + gl[0] + gh[0];
            const float Po = xgo  + ol[0] + oh[0];

            const float iv = frcp(1.f + fexp2(Pi));           // sigmoid
            const float fv = frcp(1.f + fexp2(Pf));
            const float gs = frcp(1.f + fexp2(Pg));           // sig(2*pre)
            const float ov = frcp(1.f + fexp2(Po));
            const float gv = fmaf(2.f, gs, -1.f);             // tanh
            Cs = fmaf(fv, Cs, (-2.f * L2E) * (iv * gv));      // scaled c
            const float tr = frcp(1.f + fexp2(Cs));           // = (tanh(c)+1)/2
            const float h  = fmaf(ov + ov, tr, -ov);          // ov*tanh(c)

            unsigned hu;                                      // 1-op h->bf16
            asm("v_cvt_pk_bf16_f32 %0, %1, %2" : "=v"(hu) : "v"(h), "v"(0.f));
            hb[pr ^ 1][q][unit] = (unsigned short)hu;

            // off-chain: out store (left in flight -- raw barrier never
            // drains vmcnt) + next-step xg prefetch (same-wave data)
            outp[(size_t)(T + tc) * (BATCH * HD)] = h;
            if (tc + 1 < TB) {
                xgi  = xgf[xbase[0] + tc + 1];
                xgf_ = xgf[xbase[1] + tc + 1];
                xgg  = xgf[xbase[2] + tc + 1];
                xgo  = xgf[xbase[3] + tc + 1];
            }
            wg_barrier();   // h(t) visible for t+1 (LDS-only wait)
        }
    }
}

extern "C" void kernel_launch(void* const* d_in, const int* in_sizes, int n_in,
                              void* d_out, int out_size, void* d_ws, size_t ws_size,
                              hipStream_t stream) {
    const float* x    = (const float*)d_in[0];
    const float* W_ih = (const float*)d_in[1];
    const float* W_hh = (const float*)d_in[2];
    const float* b_ih = (const float*)d_in[3];
    const float* b_hh = (const float*)d_in[4];
    float* out = (float*)d_out;

    lstm_v12<<<BATCH / NS, 256, 0, stream>>>(x, W_ih, W_hh, b_ih, b_hh, out);
}

// Round 16
// 164.864 us; speedup vs baseline: 1.0700x; 1.0700x over previous
//
#include <hip/hip_runtime.h>
#include <hip/hip_bf16.h>

#define SEQ   512
#define BATCH 1024
#define HD    64
#define NS    4      // samples per block -> 256 blocks (1 block/CU)
#define TB    16     // time-batch: steps per x-projection pass

typedef __attribute__((ext_vector_type(8))) short bf16x8;   // 8 bf16 = 4 VGPR
typedef __attribute__((ext_vector_type(4))) float f32x4;    // MFMA acc

// float -> bf16 raw bits, round-to-nearest-even
__device__ __forceinline__ unsigned short f2bf(float f) {
    unsigned u = __float_as_uint(f);
    return (unsigned short)((u + 0x7FFFu + ((u >> 16) & 1u)) >> 16);
}
__device__ __forceinline__ float frcp(float x) { return __builtin_amdgcn_rcpf(x); }
// raw v_exp_f32 (exp2), 1 instruction on the chain
__device__ __forceinline__ float fexp2(float x) {
    float r; asm("v_exp_f32 %0, %1" : "=v"(r) : "v"(x)); return r;
}

// v13 = v11's scheduling (__syncthreads; compiler-managed waitcnts -- the
// v12 raw-barrier + sched_barrier(0) pinning REGRESSED 205->224) combined
// with v12's two proven-good pieces:
//  - conflict-free xg layout ((m*16+tile)*17+col)*19+tc : per-step dword
//    reads hit 32 banks <=2-way (v11's [20]-pad was ~8-way, 13.6M cycles)
//  - c carried pre-scaled by -2log2e (one fewer chain op; absmax verified)
// Chain per step: barrier -> ds_read h (b128 x2) -> 8 independent MFMA ->
// cell (exp2/rcp form, pre-scaled weights, bias in x-pass C operand) ->
// cvt_pk_bf16 -> ds_write -> barrier.
__global__ __launch_bounds__(256, 1)
void lstm_v13(const float* __restrict__ x,
              const float* __restrict__ W_ih,
              const float* __restrict__ W_hh,
              const float* __restrict__ b_ih,
              const float* __restrict__ b_hh,
              float* __restrict__ out)
{
    __shared__ float xgf[NS * 16 * 17 * 19];                  // 80.75 KB
    __shared__ __align__(16) unsigned short xch[NS][TB][72];  // 9 KB
    __shared__ __align__(16) unsigned short hb[2][NS][80];    // 1.25 KB ping-pong h

    const int tid  = threadIdx.x;
    const int w    = tid >> 6;        // wave 0..3
    const int ln   = tid & 63;
    const int col  = ln & 15;         // MFMA col / unit within wave
    const int kg   = ln >> 4;         // k-group of fragments
    const int slot = (ln >> 2) & 3;   // A-row -> sample (v6-verified map)
    const int q    = ln >> 4;         // cell sample (D row 4q reg0)
    const int unit = w * 16 + col;
    const int sBase = blockIdx.x * NS;

    const float L2E = 1.4426950408889634f;
    const float sc[4] = { -L2E, -L2E, -2.f * L2E, -L2E };  // i,f,g,o pre-scales

    // ---- one-time: pre-scaled W_ih / W_hh B-fragments -> registers ----
    bf16x8 Bx[4][2], Bh[4][2];        // [gate][k-tile]
    #pragma unroll
    for (int g = 0; g < 4; ++g) {
        const float s = sc[g];
        #pragma unroll
        for (int kt = 0; kt < 2; ++kt) {
            const int n = (g * 4 + w) * 16 + col;
            const int k = kt * 32 + kg * 8;
            const float4 xa = *(const float4*)(W_ih + n * 64 + k);
            const float4 xb = *(const float4*)(W_ih + n * 64 + k + 4);
            const float4 ha = *(const float4*)(W_hh + n * 64 + k);
            const float4 hc = *(const float4*)(W_hh + n * 64 + k + 4);
            bf16x8 vx, vh;
            vx[0]=(short)f2bf(xa.x*s); vx[1]=(short)f2bf(xa.y*s); vx[2]=(short)f2bf(xa.z*s); vx[3]=(short)f2bf(xa.w*s);
            vx[4]=(short)f2bf(xb.x*s); vx[5]=(short)f2bf(xb.y*s); vx[6]=(short)f2bf(xb.z*s); vx[7]=(short)f2bf(xb.w*s);
            vh[0]=(short)f2bf(ha.x*s); vh[1]=(short)f2bf(ha.y*s); vh[2]=(short)f2bf(ha.z*s); vh[3]=(short)f2bf(ha.w*s);
            vh[4]=(short)f2bf(hc.x*s); vh[5]=(short)f2bf(hc.y*s); vh[6]=(short)f2bf(hc.z*s); vh[7]=(short)f2bf(hc.w*s);
            Bx[g][kt] = vx; Bh[g][kt] = vh;
        }
    }
    // pre-scaled bias -> x-pass C operand
    f32x4 bias4[4];
    #pragma unroll
    for (int g = 0; g < 4; ++g) {
        const int gg = g * 64 + unit;
        const float b = (b_ih[gg] + b_hh[gg]) * sc[g];
        bias4[g][0] = b; bias4[g][1] = b; bias4[g][2] = b; bias4[g][3] = b;
    }
    // per-lane xg read bases (loop-invariant)
    int xbase[4];
    #pragma unroll
    for (int g = 0; g < 4; ++g)
        xbase[g] = ((q * 16 + g * 4 + w) * 17 + col) * 19;

    for (int i = tid; i < (2 * NS * 80) / 2; i += 256) ((unsigned*)hb)[i] = 0;

    float Cs = 0.f;                   // c pre-scaled by -2log2e
    const f32x4 z4 = {0.f, 0.f, 0.f, 0.f};
    float* outp = out + (size_t)(sBase + q) * HD + unit;

    for (int T = 0; T < SEQ; T += TB) {
        // ---- refill x chunk: 1024 float4 / 256 thr = 4 each ----
        #pragma unroll
        for (int j = 0; j < 4; ++j) {
            const int idx = tid + j * 256;
            const int k4 = idx & 15, tt = (idx >> 4) & 15, m = idx >> 8;
            const float4 v = *(const float4*)&x[(((size_t)(T + tt) * BATCH) + sBase + m) * HD + k4 * 4];
            uint2 pk;
            pk.x = (unsigned)f2bf(v.x) | ((unsigned)f2bf(v.y) << 16);
            pk.y = (unsigned)f2bf(v.z) | ((unsigned)f2bf(v.w) << 16);
            *(uint2*)&xch[m][tt][k4 * 4] = pk;
        }
        __syncthreads();

        // ---- x-pass: per sample, A-rows = 16 timesteps; bias in C ----
        #pragma unroll
        for (int m = 0; m < NS; ++m) {
            const bf16x8 a0 = *(const bf16x8*)&xch[m][ln & 15][kg * 8];
            const bf16x8 a1 = *(const bf16x8*)&xch[m][ln & 15][32 + kg * 8];
            #pragma unroll
            for (int g = 0; g < 4; ++g) {
                f32x4 a = __builtin_amdgcn_mfma_f32_16x16x32_bf16(a0, Bx[g][0], bias4[g], 0, 0, 0);
                a = __builtin_amdgcn_mfma_f32_16x16x32_bf16(a1, Bx[g][1], a, 0, 0, 0);
                // D rows = steps 4kg..4kg+3; scalar writes (conflict-free layout)
                const int base = ((m * 16 + g * 4 + w) * 17 + col) * 19 + 4 * kg;
                xgf[base + 0] = a[0]; xgf[base + 1] = a[1];
                xgf[base + 2] = a[2]; xgf[base + 3] = a[3];
            }
        }
        // no barrier: wave w reads only tiles {4g+w} -- its own writes

        // xg prefetch for step 0 (register-carried across barriers)
        float xgi = xgf[xbase[0]];
        float xgf_ = xgf[xbase[1]];
        float xgg = xgf[xbase[2]];
        float xgo = xgf[xbase[3]];

        #pragma unroll
        for (int tc = 0; tc < TB; ++tc) {
            const int pr = tc & 1;                 // static ping-pong index
            const bf16x8 ah0 = *(const bf16x8*)&hb[pr][slot][kg * 8];
            const bf16x8 ah1 = *(const bf16x8*)&hb[pr][slot][32 + kg * 8];

            // 8 INDEPENDENT MFMAs (K-halves merged by scalar adds)
            const f32x4 il = __builtin_amdgcn_mfma_f32_16x16x32_bf16(ah0, Bh[0][0], z4, 0, 0, 0);
            const f32x4 ih = __builtin_amdgcn_mfma_f32_16x16x32_bf16(ah1, Bh[0][1], z4, 0, 0, 0);
            const f32x4 fl = __builtin_amdgcn_mfma_f32_16x16x32_bf16(ah0, Bh[1][0], z4, 0, 0, 0);
            const f32x4 fh = __builtin_amdgcn_mfma_f32_16x16x32_bf16(ah1, Bh[1][1], z4, 0, 0, 0);
            const f32x4 gl = __builtin_amdgcn_mfma_f32_16x16x32_bf16(ah0, Bh[2][0], z4, 0, 0, 0);
            const f32x4 gh = __builtin_amdgcn_mfma_f32_16x16x32_bf16(ah1, Bh[2][1], z4, 0, 0, 0);
            const f32x4 ol = __builtin_amdgcn_mfma_f32_16x16x32_bf16(ah0, Bh[3][0], z4, 0, 0, 0);
            const f32x4 oh = __builtin_amdgcn_mfma_f32_16x16x32_bf16(ah1, Bh[3][1], z4, 0, 0, 0);

            // pre-activations (already scaled by -l2e / -2l2e, bias included)
            const float Pi = xgi  + il[0] + ih[0];
            const float Pf = xgf_ + fl[0] + fh[0];
            const float Pg = xgg  + gl[0] + gh[0];
            const float Po = xgo  + ol[0] + oh[0];

            const float iv = frcp(1.f + fexp2(Pi));           // sigmoid
            const float fv = frcp(1.f + fexp2(Pf));
            const float gs = frcp(1.f + fexp2(Pg));           // sig(2*pre)
            const float ov = frcp(1.f + fexp2(Po));
            const float gv = fmaf(2.f, gs, -1.f);             // tanh
            Cs = fmaf(fv, Cs, (-2.f * L2E) * (iv * gv));      // scaled c
            const float tr = frcp(1.f + fexp2(Cs));           // = (1-tanh(c))/2 form
            const float h  = fmaf(ov + ov, tr, -ov);          // ov*tanh(c)

            unsigned hu;                                      // 1-op h->bf16
            asm("v_cvt_pk_bf16_f32 %0, %1, %2" : "=v"(hu) : "v"(h), "v"(0.f));
            hb[pr ^ 1][q][unit] = (unsigned short)hu;

            // off-chain: out store + next-step xg prefetch (same-wave data)
            outp[(size_t)(T + tc) * (BATCH * HD)] = h;
            if (tc + 1 < TB) {
                xgi  = xgf[xbase[0] + tc + 1];
                xgf_ = xgf[xbase[1] + tc + 1];
                xgg  = xgf[xbase[2] + tc + 1];
                xgo  = xgf[xbase[3] + tc + 1];
            }
            __syncthreads();   // h(t) visible for t+1
        }
    }
}

extern "C" void kernel_launch(void* const* d_in, const int* in_sizes, int n_in,
                              void* d_out, int out_size, void* d_ws, size_t ws_size,
                              hipStream_t stream) {
    const float* x    = (const float*)d_in[0];
    const float* W_ih = (const float*)d_in[1];
    const float* W_hh = (const float*)d_in[2];
    const float* b_ih = (const float*)d_in[3];
    const float* b_hh = (const float*)d_in[4];
    float* out = (float*)d_out;

    lstm_v13<<<BATCH / NS, 256, 0, stream>>>(x, W_ih, W_hh, b_ih, b_hh, out);
}

// Round 17
// 160.417 us; speedup vs baseline: 1.0997x; 1.0277x over previous
//
#include <hip/hip_runtime.h>
#include <hip/hip_bf16.h>

#define SEQ   512
#define BATCH 1024
#define HD    64
#define NS    4      // samples per block -> 256 blocks (1 block/CU)
#define TB    16     // time-batch: steps per x-projection pass

typedef __attribute__((ext_vector_type(8))) short bf16x8;   // 8 bf16 = 4 VGPR
typedef __attribute__((ext_vector_type(4))) float f32x4;    // MFMA acc

// float -> bf16 raw bits, round-to-nearest-even
__device__ __forceinline__ unsigned short f2bf(float f) {
    unsigned u = __float_as_uint(f);
    return (unsigned short)((u + 0x7FFFu + ((u >> 16) & 1u)) >> 16);
}
__device__ __forceinline__ float frcp(float x) { return __builtin_amdgcn_rcpf(x); }
// raw v_exp_f32 (exp2), 1 instruction on the chain
__device__ __forceinline__ float fexp2(float x) {
    float r; asm("v_exp_f32 %0, %1" : "=v"(r) : "v"(x)); return r;
}
// Unpinned raw barrier: drains LDS (lgkmcnt) only -- global out-stores
// (never read back) stay in flight, so the store ack is NOT on the
// per-step chain (__syncthreads would emit s_waitcnt vmcnt(0) first).
// "memory" clobber stops memory-op reordering; unlike sched_barrier(0)
// (v12's regression) it does NOT pin the instruction scheduler.
__device__ __forceinline__ void wg_barrier() {
    asm volatile("s_waitcnt lgkmcnt(0)" ::: "memory");
    __builtin_amdgcn_s_barrier();
    asm volatile("" ::: "memory");
}

// v14 = v11 (205us champion: pre-scaled weights/bias, exp2/rcp cell,
// independent K-half MFMAs, register xg prefetch, static ping-pong)
// + unpinned raw barrier. Nothing else changed (v13 showed the xg
// "conflict fix" was off-chain and its scalar writes cost x-pass time).
__global__ __launch_bounds__(256, 1)
void lstm_v14(const float* __restrict__ x,
              const float* __restrict__ W_ih,
              const float* __restrict__ W_hh,
              const float* __restrict__ b_ih,
              const float* __restrict__ b_hh,
              float* __restrict__ out)
{
    __shared__ __align__(16) float xg[NS][16][16][20];        // 80 KB [m][tile][col][step+pad]
    __shared__ __align__(16) unsigned short xch[NS][TB][72];  // 9 KB  [m][step][k+pad]
    __shared__ __align__(16) unsigned short hb[2][NS][88];    // 1.4 KB ping-pong h

    const int tid  = threadIdx.x;
    const int w    = tid >> 6;        // wave 0..3
    const int ln   = tid & 63;
    const int col  = ln & 15;         // MFMA col / unit within wave
    const int kg   = ln >> 4;         // k-group of fragments
    const int slot = (ln >> 2) & 3;   // A-row -> sample (v6-verified map)
    const int q    = ln >> 4;         // cell sample (D row 4q reg0)
    const int unit = w * 16 + col;
    const int sBase = blockIdx.x * NS;

    const float L2E = 1.4426950408889634f;
    const float sc[4] = { -L2E, -L2E, -2.f * L2E, -L2E };  // i,f,g,o pre-scales

    // ---- one-time: pre-scaled W_ih / W_hh B-fragments -> registers ----
    bf16x8 Bx[4][2], Bh[4][2];        // [gate][k-tile]
    #pragma unroll
    for (int g = 0; g < 4; ++g) {
        const float s = sc[g];
        #pragma unroll
        for (int kt = 0; kt < 2; ++kt) {
            const int n = (g * 4 + w) * 16 + col;
            const int k = kt * 32 + kg * 8;
            const float4 xa = *(const float4*)(W_ih + n * 64 + k);
            const float4 xb = *(const float4*)(W_ih + n * 64 + k + 4);
            const float4 ha = *(const float4*)(W_hh + n * 64 + k);
            const float4 hc = *(const float4*)(W_hh + n * 64 + k + 4);
            bf16x8 vx, vh;
            vx[0]=(short)f2bf(xa.x*s); vx[1]=(short)f2bf(xa.y*s); vx[2]=(short)f2bf(xa.z*s); vx[3]=(short)f2bf(xa.w*s);
            vx[4]=(short)f2bf(xb.x*s); vx[5]=(short)f2bf(xb.y*s); vx[6]=(short)f2bf(xb.z*s); vx[7]=(short)f2bf(xb.w*s);
            vh[0]=(short)f2bf(ha.x*s); vh[1]=(short)f2bf(ha.y*s); vh[2]=(short)f2bf(ha.z*s); vh[3]=(short)f2bf(ha.w*s);
            vh[4]=(short)f2bf(hc.x*s); vh[5]=(short)f2bf(hc.y*s); vh[6]=(short)f2bf(hc.z*s); vh[7]=(short)f2bf(hc.w*s);
            Bx[g][kt] = vx; Bh[g][kt] = vh;
        }
    }
    // pre-scaled bias -> x-pass C operand
    f32x4 bias4[4];
    #pragma unroll
    for (int g = 0; g < 4; ++g) {
        const int gg = g * 64 + unit;
        const float b = (b_ih[gg] + b_hh[gg]) * sc[g];
        bias4[g][0] = b; bias4[g][1] = b; bias4[g][2] = b; bias4[g][3] = b;
    }

    for (int i = tid; i < (2 * NS * 88) / 2; i += 256) ((unsigned*)hb)[i] = 0;

    float Cs = 0.f;                   // c pre-scaled by -2log2e
    const f32x4 z4 = {0.f, 0.f, 0.f, 0.f};
    float* outp = out + (size_t)(sBase + q) * HD + unit;

    for (int T = 0; T < SEQ; T += TB) {
        // ---- refill x chunk: 1024 float4 / 256 thr = 4 each ----
        #pragma unroll
        for (int j = 0; j < 4; ++j) {
            const int idx = tid + j * 256;
            const int k4 = idx & 15, tt = (idx >> 4) & 15, m = idx >> 8;
            const float4 v = *(const float4*)&x[(((size_t)(T + tt) * BATCH) + sBase + m) * HD + k4 * 4];
            uint2 pk;
            pk.x = (unsigned)f2bf(v.x) | ((unsigned)f2bf(v.y) << 16);
            pk.y = (unsigned)f2bf(v.z) | ((unsigned)f2bf(v.w) << 16);
            *(uint2*)&xch[m][tt][k4 * 4] = pk;
        }
        wg_barrier();

        // ---- x-pass: per sample, A-rows = 16 timesteps; bias in C ----
        #pragma unroll
        for (int m = 0; m < NS; ++m) {
            const bf16x8 a0 = *(const bf16x8*)&xch[m][ln & 15][kg * 8];
            const bf16x8 a1 = *(const bf16x8*)&xch[m][ln & 15][32 + kg * 8];
            #pragma unroll
            for (int g = 0; g < 4; ++g) {
                f32x4 a = __builtin_amdgcn_mfma_f32_16x16x32_bf16(a0, Bx[g][0], bias4[g], 0, 0, 0);
                a = __builtin_amdgcn_mfma_f32_16x16x32_bf16(a1, Bx[g][1], a, 0, 0, 0);
                *(f32x4*)&xg[m][g * 4 + w][col][4 * kg] = a;   // D rows = steps
            }
        }
        // no barrier: wave w reads only tiles {4g+w} -- its own writes

        // xg prefetch for step 0 (register-carried across barriers)
        float xgi = xg[q][0 * 4 + w][col][0];
        float xgf_ = xg[q][1 * 4 + w][col][0];
        float xgg = xg[q][2 * 4 + w][col][0];
        float xgo = xg[q][3 * 4 + w][col][0];

        #pragma unroll
        for (int tc = 0; tc < TB; ++tc) {
            const int pr = tc & 1;                 // static ping-pong index
            const bf16x8 ah0 = *(const bf16x8*)&hb[pr][slot][kg * 8];
            const bf16x8 ah1 = *(const bf16x8*)&hb[pr][slot][32 + kg * 8];

            // 8 INDEPENDENT MFMAs (K-halves merged by scalar adds)
            const f32x4 il = __builtin_amdgcn_mfma_f32_16x16x32_bf16(ah0, Bh[0][0], z4, 0, 0, 0);
            const f32x4 ih = __builtin_amdgcn_mfma_f32_16x16x32_bf16(ah1, Bh[0][1], z4, 0, 0, 0);
            const f32x4 fl = __builtin_amdgcn_mfma_f32_16x16x32_bf16(ah0, Bh[1][0], z4, 0, 0, 0);
            const f32x4 fh = __builtin_amdgcn_mfma_f32_16x16x32_bf16(ah1, Bh[1][1], z4, 0, 0, 0);
            const f32x4 gl = __builtin_amdgcn_mfma_f32_16x16x32_bf16(ah0, Bh[2][0], z4, 0, 0, 0);
            const f32x4 gh = __builtin_amdgcn_mfma_f32_16x16x32_bf16(ah1, Bh[2][1], z4, 0, 0, 0);
            const f32x4 ol = __builtin_amdgcn_mfma_f32_16x16x32_bf16(ah0, Bh[3][0], z4, 0, 0, 0);
            const f32x4 oh = __builtin_amdgcn_mfma_f32_16x16x32_bf16(ah1, Bh[3][1], z4, 0, 0, 0);

            // pre-activations (already scaled by -l2e / -2l2e, bias included)
            const float Pi = xgi  + il[0] + ih[0];
            const float Pf = xgf_ + fl[0] + fh[0];
            const float Pg = xgg  + gl[0] + gh[0];
            const float Po = xgo  + ol[0] + oh[0];

            const float iv = frcp(1.f + fexp2(Pi));           // sigmoid
            const float fv = frcp(1.f + fexp2(Pf));
            const float gs = frcp(1.f + fexp2(Pg));           // sig(2*pre)
            const float ov = frcp(1.f + fexp2(Po));
            const float gv = fmaf(2.f, gs, -1.f);             // tanh
            Cs = fmaf(fv, Cs, (-2.f * L2E) * (iv * gv));      // scaled c
            const float tr = frcp(1.f + fexp2(Cs));
            const float h  = fmaf(ov + ov, tr, -ov);          // ov*tanh(c)

            unsigned hu;                                      // 1-op h->bf16
            asm("v_cvt_pk_bf16_f32 %0, %1, %2" : "=v"(hu) : "v"(h), "v"(0.f));
            hb[pr ^ 1][q][unit] = (unsigned short)hu;

            // off-chain: out store (stays in flight across the raw barrier)
            // + next-step xg prefetch (same-wave data)
            outp[(size_t)(T + tc) * (BATCH * HD)] = h;
            if (tc + 1 < TB) {
                xgi  = xg[q][0 * 4 + w][col][tc + 1];
                xgf_ = xg[q][1 * 4 + w][col][tc + 1];
                xgg  = xg[q][2 * 4 + w][col][tc + 1];
                xgo  = xg[q][3 * 4 + w][col][tc + 1];
            }
            wg_barrier();   // h(t) visible for t+1 (LDS-only wait)
        }
    }
}

extern "C" void kernel_launch(void* const* d_in, const int* in_sizes, int n_in,
                              void* d_out, int out_size, void* d_ws, size_t ws_size,
                              hipStream_t stream) {
    const float* x    = (const float*)d_in[0];
    const float* W_ih = (const float*)d_in[1];
    const float* W_hh = (const float*)d_in[2];
    const float* b_ih = (const float*)d_in[3];
    const float* b_hh = (const float*)d_in[4];
    float* out = (float*)d_out;

    lstm_v14<<<BATCH / NS, 256, 0, stream>>>(x, W_ih, W_hh, b_ih, b_hh, out);
}